// Round 10
// baseline (726.730 us; speedup 1.0000x reference)
//
#include <hip/hip_runtime.h>

// ---------------------------------------------------------------------------
// VGAE encoder, MI355X. The two adj (16384x16384 f32, 1 GiB) GEMMs dominate.
// fp32 has no MFMA on CDNA4 -> split f32 into bf16 hi+lo, 3 MFMA terms
// (hi*hi + hi*lo + lo*hi), fp32 accumulate. Floor = 2 adj passes ~340us.
// R5: 724us; R9 (4 blk/CU TLP): 714us. Occupancy/depth/granularity all flat.
// Serialization model: per-wave IN-ORDER vmcnt queue serializes adj (HBM,
// ~10.4 B/cyc/CU) with B (L2, ~64 B/cyc/CU): macro cost = adjB + BB. B bytes
// per macro = Kmacro*512 FIXED; adj bytes = M*Kmacro*4. Only M changes the
// ratio. R10: M=128 (B:adj 1:1, was 4:1 in R9), grid 256 = 128mt x splitK2
// = 1 block/CU, 512 thr, 32 macros K=256, single 128KB LDS, 1KB wave bursts.
// ---------------------------------------------------------------------------

typedef __bf16 bf16_t;
typedef __attribute__((ext_vector_type(4))) __bf16 bf16x4;
typedef __attribute__((ext_vector_type(8))) __bf16 bf16x8;
typedef __attribute__((ext_vector_type(16))) float f32x16;
typedef __attribute__((ext_vector_type(4)))  float f32x4;

#define N_NODES 16384
#define MFMA3(ACC, A, B) \
    ACC = __builtin_amdgcn_mfma_f32_32x32x16_bf16(A, B, ACC, 0, 0, 0)

// Fragment layout for the B operand of mfma_f32_32x32x16_bf16:
// element (k=r, col=c) -> 1KiB units indexed by (K16 = r>>4, cblk = c>>5),
// within a unit: lane = (c&31) + 32*((r>>3)&1) holds 8 bf16 (k = ..8g..8g+7).
__device__ __forceinline__ int frag_off(int r, int c) {
    int K16  = r >> 4;
    int cblk = c >> 5;
    int g    = (r >> 3) & 1;
    int lane = (c & 31) + (g << 5);
    return ((K16 * 4 + cblk) << 9) + (lane << 3) + (r & 7);
}

__device__ __forceinline__ float4 relu_add4(float4 a, float4 b) {
    float4 r;
    r.x = fmaxf(a.x + b.x, 0.f); r.y = fmaxf(a.y + b.y, 0.f);
    r.z = fmaxf(a.z + b.z, 0.f); r.w = fmaxf(a.w + b.w, 0.f);
    return r;
}

// ---------------------------------------------------------------------------
// Small fp32 GEMM producer: out = A[16384][K] @ W[K][128]; epilogue splits
// each output into bf16 hi/lo and scatters into the fragment layout.
// ADD2: A := relu(A + A2) elementwise (fused partial-reduce of the hidden).
// ---------------------------------------------------------------------------
template<int K, bool FUSED, bool ADD2>
__global__ __launch_bounds__(256)
void producer_kernel(const float* __restrict__ A,
                     const float* __restrict__ A2,
                     const float* __restrict__ W,
                     const float* __restrict__ Wa,
                     const float* __restrict__ Wb,
                     bf16_t* __restrict__ Bh,
                     bf16_t* __restrict__ Bl)
{
    __shared__ float As[32][128];   // k-major A tile: As[k][r]
    __shared__ float Wsh[32][128];  // Wsh[k][c]
    const int t    = threadIdx.x;
    const int row0 = blockIdx.x * 128;
    const int tc   = t & 15, tr = t >> 4;   // 16x16 thread grid, 8x8 outs each

    float acc[8][8];
    #pragma unroll
    for (int i = 0; i < 8; ++i)
        #pragma unroll
        for (int j = 0; j < 8; ++j) acc[i][j] = 0.f;

    const int ra = t >> 1, ks = (t & 1) << 4;   // A staging: 16 f32/thread
    const int wk = t >> 3, wc = (t & 7) << 4;   // W staging: 16 f32/thread

    for (int k0 = 0; k0 < K; k0 += 32) {
        const float* ap = A + (size_t)(row0 + ra) * K + k0 + ks;
        float4 a0 = *(const float4*)(ap);
        float4 a1 = *(const float4*)(ap + 4);
        float4 a2 = *(const float4*)(ap + 8);
        float4 a3 = *(const float4*)(ap + 12);
        if (ADD2) {
            const float* ap2 = A2 + (size_t)(row0 + ra) * K + k0 + ks;
            a0 = relu_add4(a0, *(const float4*)(ap2));
            a1 = relu_add4(a1, *(const float4*)(ap2 + 4));
            a2 = relu_add4(a2, *(const float4*)(ap2 + 8));
            a3 = relu_add4(a3, *(const float4*)(ap2 + 12));
        }
        float4 w0, w1, w2, w3;
        if (!FUSED) {
            const float* wp = W + (size_t)(k0 + wk) * 128 + wc;
            w0 = *(const float4*)(wp);     w1 = *(const float4*)(wp + 4);
            w2 = *(const float4*)(wp + 8); w3 = *(const float4*)(wp + 12);
        } else {
            const float* wp = (wc < 64) ? (Wa + (size_t)(k0 + wk) * 64 + wc)
                                        : (Wb + (size_t)(k0 + wk) * 64 + (wc - 64));
            w0 = *(const float4*)(wp);     w1 = *(const float4*)(wp + 4);
            w2 = *(const float4*)(wp + 8); w3 = *(const float4*)(wp + 12);
        }
        __syncthreads();   // previous iteration's compute done before overwrite
        {
            float tmp[16] = {a0.x,a0.y,a0.z,a0.w, a1.x,a1.y,a1.z,a1.w,
                             a2.x,a2.y,a2.z,a2.w, a3.x,a3.y,a3.z,a3.w};
            #pragma unroll
            for (int j = 0; j < 16; ++j) As[ks + j][ra] = tmp[j];
            *(float4*)&Wsh[wk][wc     ] = w0;
            *(float4*)&Wsh[wk][wc +  4] = w1;
            *(float4*)&Wsh[wk][wc +  8] = w2;
            *(float4*)&Wsh[wk][wc + 12] = w3;
        }
        __syncthreads();
        #pragma unroll 4
        for (int k = 0; k < 32; ++k) {
            float av[8], wv[8];
            *(float4*)&av[0] = *(const float4*)&As[k][8 * tr];
            *(float4*)&av[4] = *(const float4*)&As[k][8 * tr + 4];
            *(float4*)&wv[0] = *(const float4*)&Wsh[k][8 * tc];
            *(float4*)&wv[4] = *(const float4*)&Wsh[k][8 * tc + 4];
            #pragma unroll
            for (int i = 0; i < 8; ++i)
                #pragma unroll
                for (int j = 0; j < 8; ++j)
                    acc[i][j] = fmaf(av[i], wv[j], acc[i][j]);
        }
    }

    #pragma unroll
    for (int i = 0; i < 8; ++i) {
        int r = row0 + 8 * tr + i;
        #pragma unroll
        for (int j = 0; j < 8; ++j) {
            int c = 8 * tc + j;
            float v = acc[i][j];
            bf16_t h = (bf16_t)v;
            bf16_t l = (bf16_t)(v - (float)h);
            int off = frag_off(r, c);
            Bh[off] = h;
            Bl[off] = l;
        }
    }
}

// ---------------------------------------------------------------------------
// Big kernel: P_kh = adj[rows, kh-half] @ B[kh-half], M-tile 128, K-half 8192.
// grid 256 (128 mt x 2 kh) = 1 block/CU, 512 thr (8 waves = 2 row-half x
// 4 col-quadrant, 2 stacked 32x32 tiles each). 32 macros of K=256;
// single-buffer LDS [128][256] hi+lo = 128 KB. adj: wave w stages rows
// w*16..w*16+15, one 1KB dwordx4 burst per row per macro (16 insts/wave).
// B: 2 reg sets interleaved with compute, 4 subs/macro. Two lgkm-only
// barriers per macro. B:adj bytes per macro = 1:1 (the R10 lever).
// LDS swizzle: elem (r,k) at (r<<8) + (((k>>4) ^ (r&15))<<4) + (k&15).
// ---------------------------------------------------------------------------
struct BSet { bf16x8 h[4]; bf16x8 l[4]; };   // 32 VGPRs

__global__ __launch_bounds__(512, 2)
void adj_gemm_kernel(const float* __restrict__ adj,
                     const bf16_t* __restrict__ Bh,
                     const bf16_t* __restrict__ Bl,
                     float* __restrict__ P0,
                     float* __restrict__ P1)
{
    __shared__ __align__(16) bf16_t AsH[128 * 256];
    __shared__ __align__(16) bf16_t AsL[128 * 256];
    const int t    = threadIdx.x;
    const int lane = t & 63;
    const int w    = t >> 6;
    const int mt   = blockIdx.x >> 1;
    const int kh   = blockIdx.x & 1;
    const int row0 = mt << 7;
    const int hi32 = lane >> 5;
    float* const outP = kh ? P1 : P0;

    // adj staging: wave w stages rows w*16+j (j=0..15), one wave-wide
    // dwordx4 burst per row (64 lanes x 16B = 1KB contiguous per macro).
    const float* aBase = adj + (size_t)(row0 + (w << 4)) * 16384
                             + (kh << 13) + (lane << 2);

    // LDS write indices: row = w*16+j, elems k = lane*4..+3
    int wIdx[16];
    #pragma unroll
    for (int j = 0; j < 16; ++j) {
        int row = (w << 4) + j;
        wIdx[j] = (row << 8) + ((((lane >> 2) ^ (row & 15)) << 4)
                                + ((lane & 3) << 2));
    }

    // A-frag reads: wave = (row-half rh = w>>2, col-quadrant cq = w&3);
    // two stacked tiles: rows frow, frow+32. k-unit u = sub*4+k16.
    const int rh   = w >> 2, cq = w & 3;
    const int frow = (rh << 6) + (lane & 31);
    const int rbase0 = (frow << 8) + (hi32 << 3);
    const int rbase1 = ((frow + 32) << 8) + (hi32 << 3);
    const int rx     = frow & 15;            // (frow+32)&15 == frow&15

    // B frag per-thread base; sub (K=64) stride = 8192 elems
    const int tb   = (cq << 9) + (lane << 3);
    const int sub0 = kh << 7;                // kh*128 subs

    f32x16 acc0, acc1;
    #pragma unroll
    for (int i = 0; i < 16; ++i) { acc0[i] = 0.f; acc1[i] = 0.f; }

    f32x4 ar[16];
    BSet S0, S1;

    auto loadAdj = [&](int mac) {
        const float* p = aBase + (mac << 8);
        #pragma unroll
        for (int j = 0; j < 16; ++j)
            ar[j] = __builtin_nontemporal_load((const f32x4*)(p + (size_t)j * 16384));
    };
    auto cvtWrite = [&]() {
        #pragma unroll
        for (int j = 0; j < 16; ++j) {
            bf16x4 hv, lv;
            #pragma unroll
            for (int e = 0; e < 4; ++e) {
                float v = ar[j][e];
                bf16_t h = (bf16_t)v;
                hv[e] = h;
                lv[e] = (bf16_t)(v - (float)h);
            }
            *(bf16x4*)&AsH[wIdx[j]] = hv;
            *(bf16x4*)&AsL[wIdx[j]] = lv;
        }
    };
    auto loadB = [&](BSet& S, int sub) {
        const size_t base = ((size_t)sub << 13) + tb;
        #pragma unroll
        for (int s = 0; s < 4; ++s) {
            S.h[s] = *(const bf16x8*)(Bh + base + (s << 11));
            S.l[s] = *(const bf16x8*)(Bl + base + (s << 11));
        }
    };
    auto computeS = [&](const BSet& S, int s) {
        #pragma unroll
        for (int k16 = 0; k16 < 4; ++k16) {
            const int u  = (s << 2) + k16;
            const int o  = (u ^ rx) << 4;
            bf16x8 ah0 = *(const bf16x8*)&AsH[rbase0 + o];
            bf16x8 al0 = *(const bf16x8*)&AsL[rbase0 + o];
            bf16x8 ah1 = *(const bf16x8*)&AsH[rbase1 + o];
            bf16x8 al1 = *(const bf16x8*)&AsL[rbase1 + o];
            MFMA3(acc0, ah0, S.h[k16]);
            MFMA3(acc1, ah1, S.h[k16]);
            MFMA3(acc0, ah0, S.l[k16]);
            MFMA3(acc1, ah1, S.l[k16]);
            MFMA3(acc0, al0, S.h[k16]);
            MFMA3(acc1, al1, S.h[k16]);
        }
    };

    // lgkm-only barrier: ds ops drained; register-dest global loads stay in
    // flight across the barrier (counted vmcnt by compiler).
#define SYNC_LDS() do { asm volatile("s_waitcnt lgkmcnt(0)" ::: "memory"); \
                        __builtin_amdgcn_s_barrier(); } while (0)

    loadAdj(0);
    for (int m = 0; m < 32; ++m) {
        cvtWrite();                          // waits ar = adj(m)
        SYNC_LDS();                          // staged tile visible
        const int sb = sub0 + (m << 2);
        loadB(S0, sb + 0);
        if (m < 31) loadAdj(m + 1);          // in flight across the macro
        computeS(S0, 0);
        loadB(S1, sb + 1);  computeS(S1, 1);
        loadB(S0, sb + 2);  computeS(S0, 2);
        loadB(S1, sb + 3);  computeS(S1, 3);
        SYNC_LDS();                          // reads done before overwrite
    }
#undef SYNC_LDS

    // C write: col = cq*32 + lane&31; rows rw+{0,32} per 32x32 C map
    const int col = (cq << 5) + (lane & 31);
    const int rw  = row0 + (rh << 6) + (hi32 << 2);
    #pragma unroll
    for (int q = 0; q < 16; ++q) {
        int r = rw + (q & 3) + ((q >> 2) << 3);
        outP[(size_t)r * 128 + col]        = acc0[q];
        outP[(size_t)(r + 32) * 128 + col] = acc1[q];
    }
}

// ---------------------------------------------------------------------------
// Final: T = T0+T1 ([16384][128], Z cols 0-63 | logstd cols 64-127);
// mean = Z@Wp + bp; out = noise*exp(min(logstd,10)) + mean
// ---------------------------------------------------------------------------
__global__ __launch_bounds__(256)
void final_kernel(const float* __restrict__ T0,
                  const float* __restrict__ T1,
                  const float* __restrict__ Wp,
                  const float* __restrict__ bp,
                  const float* __restrict__ noise,
                  float* __restrict__ out)
{
    __shared__ float Wps[64][64];
    __shared__ float Ts[64][64];
    const int t = threadIdx.x;
    const int row0 = blockIdx.x * 64;
    {
        int k = t >> 2, c0 = (t & 3) << 4;
        #pragma unroll
        for (int i = 0; i < 4; ++i)
            *(float4*)&Wps[k][c0 + 4 * i] = *(const float4*)&Wp[(size_t)k * 64 + c0 + 4 * i];
        #pragma unroll
        for (int i = 0; i < 4; ++i) {
            float4 z0 = *(const float4*)&T0[(size_t)(row0 + k) * 128 + c0 + 4 * i];
            float4 z1 = *(const float4*)&T1[(size_t)(row0 + k) * 128 + c0 + 4 * i];
            float4 zs; zs.x = z0.x + z1.x; zs.y = z0.y + z1.y;
            zs.z = z0.z + z1.z; zs.w = z0.w + z1.w;
            *(float4*)&Ts[k][c0 + 4 * i] = zs;
        }
    }
    __syncthreads();

    const int r  = t >> 2;
    const int c0 = (t & 3) << 4;
    float acc[16];
    #pragma unroll
    for (int j = 0; j < 16; ++j) acc[j] = bp[c0 + j];
    for (int k = 0; k < 64; ++k) {
        float a = Ts[r][k];
        #pragma unroll
        for (int j = 0; j < 16; ++j) acc[j] = fmaf(a, Wps[k][c0 + j], acc[j]);
    }
    const int grow = row0 + r;
    #pragma unroll
    for (int j = 0; j < 16; ++j) {
        size_t li = (size_t)grow * 128 + 64 + c0 + j;
        float ls = T0[li] + T1[li];
        ls = fminf(ls, 10.0f);
        out[(size_t)grow * 64 + c0 + j] =
            noise[(size_t)grow * 64 + c0 + j] * __expf(ls) + acc[j];
    }
}

// ---------------------------------------------------------------------------
extern "C" void kernel_launch(void* const* d_in, const int* in_sizes, int n_in,
                              void* d_out, int out_size, void* d_ws, size_t ws_size,
                              hipStream_t stream) {
    const float* X     = (const float*)d_in[0];
    const float* adj   = (const float*)d_in[1];
    const float* W1    = (const float*)d_in[2];
    const float* Wm    = (const float*)d_in[3];
    const float* Wsv   = (const float*)d_in[4];
    const float* Wp    = (const float*)d_in[5];
    const float* bp    = (const float*)d_in[6];
    const float* noise = (const float*)d_in[7];
    float* out = (float*)d_out;

    char* ws = (char*)d_ws;
    bf16_t* Bh = (bf16_t*)ws;                     // 4 MB
    bf16_t* Bl = (bf16_t*)(ws + (4u << 20));      // 4 MB
    float*  P0 = (float*)(ws + (8u << 20));       // 8 MB partial (kh=0)
    float*  P1 = (float*)(ws + (16u << 20));      // 8 MB partial (kh=1)

    // S1: B1 = fragsplit((X @ W1)^T)
    producer_kernel<256, false, false><<<128, 256, 0, stream>>>(
        X, nullptr, W1, nullptr, nullptr, Bh, Bl);
    // S2: hidden partials: P_kh = adj[:, kh-half] @ B1[kh-half]
    adj_gemm_kernel<<<256, 512, 0, stream>>>(adj, Bh, Bl, P0, P1);
    // S3: B2 = fragsplit((relu(P0+P1) @ [Wm|Ws])^T)   (reduce+relu fused)
    producer_kernel<128, true, true><<<128, 256, 0, stream>>>(
        P0, P1, nullptr, Wm, Wsv, Bh, Bl);
    // S4: T partials
    adj_gemm_kernel<<<256, 512, 0, stream>>>(adj, Bh, Bl, P0, P1);
    // S5: epilogue (T = P0+P1 summed on the fly)
    final_kernel<<<256, 256, 0, stream>>>(P0, P1, Wp, bp, noise, out);
}